// Round 8
// baseline (684.909 us; speedup 1.0000x reference)
//
#include <hip/hip_runtime.h>
#include <math.h>

#define NNODE 10000
#define INCH  9998
#define NEDGE 320000
#define KPADW 10240        // padded K (160 chunks of 64)
#define KSPLIT 4
#define KRANGE 2560        // K per block
#define NCH   40           // chunks per block (64 k each)
#define CHW   10880        // live halves per W chunk image: 2*80*68
#define CHWP  11264        // padded chunk stride: 22 segments x 1024B
#define ZN    1000064      // floats in the contiguous zero block [xl1..gat2]

typedef _Float16 half8 __attribute__((ext_vector_type(8)));
typedef float    f32x4 __attribute__((ext_vector_type(4)));

__device__ __forceinline__ float lrelu(float v){ return v > 0.f ? v : 0.2f*v; }
__device__ __forceinline__ float frelu(float v){ return v > 0.f ? v : 0.f; }

#define GLOAD_LDS16(g, l) __builtin_amdgcn_global_load_lds( \
    (const __attribute__((address_space(1))) unsigned int*)(g), \
    (__attribute__((address_space(3))) unsigned int*)(l), 16, 0, 0)

// ---------------------------------------------------------------------------
// Weight prep: Wimg[chunk][sp][col][k68] per-64k-chunk LDS images (padded to
// 22x1024B segments so k1 stages with WAVE-UNIFORM global_load_lds dests).
// sp0=fp16 hi, sp1=2048-scaled residual. Also zero-inits the accum block.
__global__ void prep_wt(const float* __restrict__ Wl, const float* __restrict__ Wr,
                        const float* __restrict__ We, _Float16* __restrict__ Wimg,
                        float* __restrict__ zblk){
  int idx = blockIdx.x*256 + threadIdx.x;
  if (idx < ZN) zblk[idx] = 0.f;
  if (idx >= 160*CHWP) return;
  int ci   = idx / CHWP;
  int rem  = idx - ci*CHWP;
  float v = 0.f;
  int valid = 0;
  if (rem < CHW){
    int sp   = rem / 5440;
    int rem2 = rem - sp*5440;
    int col  = rem2 / 68;
    int k68  = rem2 - col*68;
    int k    = ci*64 + k68;
    if (k68 < 64 && k < INCH){
      v = (col < 8) ? Wl[k*8 + col] : (col < 16 ? Wr[k*8 + (col-8)] : We[k*64 + (col-16)]);
      valid = sp + 1;
    }
  }
  _Float16 h = (_Float16)v;
  Wimg[idx] = (valid == 2) ? (_Float16)((v - (float)h) * 2048.f) : h; // valid==0 -> v=0 -> h=0
}

// ---------------------------------------------------------------------------
// Fused 80-col GEMM over x via mfma_f32_16x16x32_f16, split-fp16 (hi+lo/2048).
// Grid: 628 = 157 row-blocks (64 rows) x 4 K-splits. Block: 256 thr = 4 waves,
// each wave 16 rows x 80 cols (5 col-tiles). No per-thread arrays (rule #20);
// STAGE uses wave-uniform LDS dests (m104) — r7's per-lane dest was the
// likely waterfall serializer (all pipes <7% at 309us).
#define TILE(T, AH, AL, LB, KOFF, H, L) { \
  half8 bh = *(const half8*)((LB) + (16*(T)+c0)*68 + (KOFF)); \
  half8 bl = *(const half8*)((LB) + 5440 + (16*(T)+c0)*68 + (KOFF)); \
  H = __builtin_amdgcn_mfma_f32_16x16x32_f16(AH, bh, H, 0, 0, 0); \
  L = __builtin_amdgcn_mfma_f32_16x16x32_f16(AH, bl, L, 0, 0, 0); \
  L = __builtin_amdgcn_mfma_f32_16x16x32_f16(AL, bh, L, 0, 0, 0); }

#define KSTEP(XA, XB, XC, XD, LB, KOFF) { \
  _Float16 h0_=(_Float16)XA.x, h1_=(_Float16)XA.y, h2_=(_Float16)XB.x, h3_=(_Float16)XB.y; \
  _Float16 h4_=(_Float16)XC.x, h5_=(_Float16)XC.y, h6_=(_Float16)XD.x, h7_=(_Float16)XD.y; \
  half8 ah = {h0_,h1_,h2_,h3_,h4_,h5_,h6_,h7_}; \
  half8 al = {(_Float16)((XA.x-(float)h0_)*2048.f), (_Float16)((XA.y-(float)h1_)*2048.f), \
              (_Float16)((XB.x-(float)h2_)*2048.f), (_Float16)((XB.y-(float)h3_)*2048.f), \
              (_Float16)((XC.x-(float)h4_)*2048.f), (_Float16)((XC.y-(float)h5_)*2048.f), \
              (_Float16)((XD.x-(float)h6_)*2048.f), (_Float16)((XD.y-(float)h7_)*2048.f)}; \
  TILE(0, ah, al, LB, KOFF, ach0, acl0) \
  TILE(1, ah, al, LB, KOFF, ach1, acl1) \
  TILE(2, ah, al, LB, KOFF, ach2, acl2) \
  TILE(3, ah, al, LB, KOFF, ach3, acl3) \
  TILE(4, ah, al, LB, KOFF, ach4, acl4) }

// Wave-uniform staging: wave wv covers segments wv*6+i (i=0..5), seg<22.
// Global src carries the lane offset; LDS dest is the segment base (HW adds
// lane*16B) — the m97-verified global_load_lds pattern.
#define STAGE(CI, DB) { \
  const _Float16* wsrc = Wimg + (size_t)(CI)*CHWP; \
  _Float16* dstb = ldsb + (DB)*CHWP; \
  _Pragma("unroll") \
  for (int i_ = 0; i_ < 6; ++i_){ \
    int seg_ = wv*6 + i_; \
    if (seg_ < 22) \
      GLOAD_LDS16(wsrc + seg_*512 + lane*8, dstb + seg_*512); \
  } }

#define XLOAD(X0, X1, X2, X3, X4, X5, X6, X7, KB) { \
  X0 = *(const float2*)(x + min(xbase + (KB)     , maxi)); \
  X1 = *(const float2*)(x + min(xbase + (KB) +  2, maxi)); \
  X2 = *(const float2*)(x + min(xbase + (KB) +  4, maxi)); \
  X3 = *(const float2*)(x + min(xbase + (KB) +  6, maxi)); \
  X4 = *(const float2*)(x + min(xbase + (KB) + 32, maxi)); \
  X5 = *(const float2*)(x + min(xbase + (KB) + 34, maxi)); \
  X6 = *(const float2*)(x + min(xbase + (KB) + 36, maxi)); \
  X7 = *(const float2*)(x + min(xbase + (KB) + 38, maxi)); }

#define EPI(T, H, L) { \
  int col = 16*(T) + c0; \
  float v0 = H[0] + L[0]*inv2048; \
  float v1 = H[1] + L[1]*inv2048; \
  float v2 = H[2] + L[2]*inv2048; \
  float v3 = H[3] + L[3]*inv2048; \
  if (kh == 0){ \
    float bb = (col < 8) ? bl1[col] : (col < 16 ? br1[col-8] : 0.f); \
    v0 += bb; v1 += bb; v2 += bb; v3 += bb; \
  } \
  float* dst; int st; \
  if (col < 8)       { dst = xl1 + nodeb*8 + col;        st = 8; } \
  else if (col < 16) { dst = xr1 + nodeb*8 + col - 8;    st = 8; } \
  else               { dst = encp + nodeb*64 + col - 16; st = 64; } \
  atomicAdd(dst,        v0); \
  atomicAdd(dst + st,   v1); \
  atomicAdd(dst + 2*st, v2); \
  atomicAdd(dst + 3*st, v3); }

__global__ __launch_bounds__(256, 2)
void k1_fused(const float* __restrict__ x, const _Float16* __restrict__ Wimg,
              const float* __restrict__ bl1, const float* __restrict__ br1,
              float* __restrict__ xl1, float* __restrict__ xr1,
              float* __restrict__ encp){
  __shared__ _Float16 ldsbuf[2*CHWP];
  _Float16* ldsb = ldsbuf;
  const int tid  = threadIdx.x;
  const int lane = tid & 63;
  const int wv   = tid >> 6;            // 0..3
  const int g    = lane >> 4;           // k-group 0..3
  const int c0   = lane & 15;
  const int kh   = blockIdx.x & (KSPLIT-1);
  const int rb   = blockIdx.x >> 2;     // 0..156
  const int ci0  = kh*NCH;              // first global chunk id
  const int k0b  = kh*KRANGE;
  const int maxi = NNODE*INCH - 2;

  const int arow  = rb*64 + wv*16 + c0;
  const int xbase = (arow < NNODE ? arow : NNODE-1)*INCH;

  f32x4 ach0={0,0,0,0}, ach1={0,0,0,0}, ach2={0,0,0,0}, ach3={0,0,0,0}, ach4={0,0,0,0};
  f32x4 acl0={0,0,0,0}, acl1={0,0,0,0}, acl2={0,0,0,0}, acl3={0,0,0,0}, acl4={0,0,0,0};

  // prologue: stage chunk 0 into buf 0; prefetch x chunk 0 into named regs
  STAGE(ci0, 0);
  float2 xn0,xn1,xn2,xn3,xn4,xn5,xn6,xn7;
  XLOAD(xn0,xn1,xn2,xn3,xn4,xn5,xn6,xn7, k0b + 8*g);

  for (int c = 0; c < NCH; ++c){
    const int cur = c & 1;
    __syncthreads();                    // drains vmcnt(0): stage(c) + xn landed

    if (c + 1 < NCH) STAGE(ci0 + c + 1, cur^1);   // async into other buffer

    float2 xv0=xn0, xv1=xn1, xv2=xn2, xv3=xn3, xv4=xn4, xv5=xn5, xv6=xn6, xv7=xn7;
    if (c + 1 < NCH)
      XLOAD(xn0,xn1,xn2,xn3,xn4,xn5,xn6,xn7, k0b + (c+1)*64 + 8*g);

    const _Float16* lb = ldsb + cur*CHWP;
    KSTEP(xv0, xv1, xv2, xv3, lb, g*8);          // K-step s=0
    KSTEP(xv4, xv5, xv6, xv7, lb, 32 + g*8);     // K-step s=1
  }

  // epilogue: C/D layout col=lane&15, row=4*(lane>>4)+reg  [m89-verified]
  const float inv2048 = 4.8828125e-4f;
  const int nodeb = rb*64 + wv*16 + 4*g;
  if (nodeb + 3 < NNODE){
    EPI(0, ach0, acl0) EPI(1, ach1, acl1) EPI(2, ach2, acl2)
    EPI(3, ach3, acl3) EPI(4, ach4, acl4)
  } else {
    #define EPIG(T, H, L) { \
      int col = 16*(T) + c0; \
      float b0 = (kh==0) ? ((col<8)?bl1[col]:(col<16?br1[col-8]:0.f)) : 0.f; \
      float vv0 = H[0] + L[0]*inv2048 + b0; \
      float vv1 = H[1] + L[1]*inv2048 + b0; \
      float vv2 = H[2] + L[2]*inv2048 + b0; \
      float vv3 = H[3] + L[3]*inv2048 + b0; \
      int base; float* dst; int st; \
      if (col < 8)       { dst = xl1;  base = col;      st = 8; } \
      else if (col < 16) { dst = xr1;  base = col - 8;  st = 8; } \
      else               { dst = encp; base = col - 16; st = 64; } \
      if (nodeb     < NNODE) atomicAdd(dst + (nodeb  )*st + base, vv0); \
      if (nodeb + 1 < NNODE) atomicAdd(dst + (nodeb+1)*st + base, vv1); \
      if (nodeb + 2 < NNODE) atomicAdd(dst + (nodeb+2)*st + base, vv2); \
      if (nodeb + 3 < NNODE) atomicAdd(dst + (nodeb+3)*st + base, vv3); }
    EPIG(0, ach0, acl0) EPIG(1, ach1, acl1) EPIG(2, ach2, acl2)
    EPIG(3, ach3, acl3) EPIG(4, ach4, acl4)
  }
}

// ---------------------------------------------------------------------------
// conv1 edge pass A: logits -> exp -> store + denom. (No max subtraction:
// logits are O(1); exp safe in fp32; softmax is shift-invariant.)
__global__ void edgeA1(const int* __restrict__ ei, const float* __restrict__ xl,
                       const float* __restrict__ xr, const float* __restrict__ att,
                       float* __restrict__ elog, float* __restrict__ denom){
  int e = blockIdx.x*blockDim.x + threadIdx.x;
  if (e >= NEDGE + NNODE) return;
  int sN, dN;
  if (e < NEDGE) { sN = ei[e]; dN = ei[NEDGE + e]; } else { sN = dN = e - NEDGE; }
  const float4 a0 = *(const float4*)(xl + sN*8);
  const float4 a1 = *(const float4*)(xl + sN*8 + 4);
  const float4 b0 = *(const float4*)(xr + dN*8);
  const float4 b1 = *(const float4*)(xr + dN*8 + 4);
  float l0 = att[0]*lrelu(a0.x+b0.x) + att[1]*lrelu(a0.y+b0.y)
           + att[2]*lrelu(a0.z+b0.z) + att[3]*lrelu(a0.w+b0.w);
  float l1 = att[4]*lrelu(a1.x+b1.x) + att[5]*lrelu(a1.y+b1.y)
           + att[6]*lrelu(a1.z+b1.z) + att[7]*lrelu(a1.w+b1.w);
  float e0 = expf(l0), e1 = expf(l1);
  elog[e*2]   = e0;
  elog[e*2+1] = e1;
  atomicAdd(denom + dN*2,     e0);
  atomicAdd(denom + dN*2 + 1, e1);
}

__global__ void edgeB1(const int* __restrict__ ei, const float* __restrict__ elog,
                       const float* __restrict__ denom, const float* __restrict__ xl,
                       float* __restrict__ gat){
  int e = blockIdx.x*blockDim.x + threadIdx.x;
  if (e >= NEDGE + NNODE) return;
  int sN, dN;
  if (e < NEDGE) { sN = ei[e]; dN = ei[NEDGE + e]; } else { sN = dN = e - NEDGE; }
  float al0 = elog[e*2]   / denom[dN*2];
  float al1 = elog[e*2+1] / denom[dN*2 + 1];
  const float4 a0 = *(const float4*)(xl + sN*8);
  const float4 a1 = *(const float4*)(xl + sN*8 + 4);
  atomicAdd(gat + dN*8 + 0, a0.x*al0);
  atomicAdd(gat + dN*8 + 1, a0.y*al0);
  atomicAdd(gat + dN*8 + 2, a0.z*al0);
  atomicAdd(gat + dN*8 + 3, a0.w*al0);
  atomicAdd(gat + dN*8 + 4, a1.x*al1);
  atomicAdd(gat + dN*8 + 5, a1.y*al1);
  atomicAdd(gat + dN*8 + 6, a1.z*al1);
  atomicAdd(gat + dN*8 + 7, a1.w*al1);
}

// x1 = relu(gat1+bias1)@lin1_W + lin1_b
__global__ void node_x1(const float* __restrict__ gat, const float* __restrict__ bias1,
                        const float* __restrict__ linW, const float* __restrict__ linb,
                        float* __restrict__ x1){
  int n = blockIdx.x*blockDim.x + threadIdx.x;
  if (n >= NNODE) return;
  float sacc = linb[0];
  #pragma unroll
  for (int c = 0; c < 8; ++c)
    sacc = fmaf(frelu(gat[n*8+c] + bias1[c]), linW[c], sacc);
  x1[n] = sacc;
}

// conv2 is rank-1: per-endpoint features recomputed from scalar x1.
__global__ void edgeA2(const int* __restrict__ ei, const float* __restrict__ x1,
                       const float* __restrict__ Wl2, const float* __restrict__ bl2,
                       const float* __restrict__ Wr2, const float* __restrict__ br2,
                       const float* __restrict__ att,
                       float* __restrict__ elog, float* __restrict__ denom){
  int e = blockIdx.x*blockDim.x + threadIdx.x;
  if (e >= NEDGE + NNODE) return;
  int sN, dN;
  if (e < NEDGE) { sN = ei[e]; dN = ei[NEDGE + e]; } else { sN = dN = e - NEDGE; }
  float xs = x1[sN], xd = x1[dN];
  float l0 = 0.f, l1 = 0.f;
  #pragma unroll
  for (int c = 0; c < 4; ++c) {
    l0 = fmaf(att[c],   lrelu(fmaf(xs, Wl2[c],   bl2[c])   + fmaf(xd, Wr2[c],   br2[c])),   l0);
    l1 = fmaf(att[4+c], lrelu(fmaf(xs, Wl2[4+c], bl2[4+c]) + fmaf(xd, Wr2[4+c], br2[4+c])), l1);
  }
  float e0 = expf(l0), e1 = expf(l1);
  elog[e*2]   = e0;
  elog[e*2+1] = e1;
  atomicAdd(denom + dN*2,     e0);
  atomicAdd(denom + dN*2 + 1, e1);
}

__global__ void edgeB2(const int* __restrict__ ei, const float* __restrict__ elog,
                       const float* __restrict__ denom, const float* __restrict__ x1,
                       const float* __restrict__ Wl2, const float* __restrict__ bl2,
                       float* __restrict__ gat){
  int e = blockIdx.x*blockDim.x + threadIdx.x;
  if (e >= NEDGE + NNODE) return;
  int sN, dN;
  if (e < NEDGE) { sN = ei[e]; dN = ei[NEDGE + e]; } else { sN = dN = e - NEDGE; }
  float al0 = elog[e*2]   / denom[dN*2];
  float al1 = elog[e*2+1] / denom[dN*2 + 1];
  float xs = x1[sN];
  #pragma unroll
  for (int c = 0; c < 4; ++c) {
    atomicAdd(gat + dN*8 + c,     fmaf(xs, Wl2[c],   bl2[c])  *al0);
    atomicAdd(gat + dN*8 + 4 + c, fmaf(xs, Wl2[4+c], bl2[4+c])*al1);
  }
}

// ---------------------------------------------------------------------------
// x2 inline; h1 = relu(encp + x1*W1[9998] + x2*W1[9999] + b1);
// h2 = relu(h1@W2+b2); out = h2@W3 + b3.  One node per wave.
__global__ void enc_finish(const float* __restrict__ encp, const float* __restrict__ x1,
                           const float* __restrict__ gat2, const float* __restrict__ bias2,
                           const float* __restrict__ l2W, const float* __restrict__ l2b,
                           const float* __restrict__ W1, const float* __restrict__ b1,
                           const float* __restrict__ W2, const float* __restrict__ b2,
                           const float* __restrict__ W3, const float* __restrict__ b3,
                           float* __restrict__ out){
  __shared__ float hb[4][64];
  int wv = threadIdx.x >> 6, lane = threadIdx.x & 63;
  int n = blockIdx.x*4 + wv;
  float x2v = l2b[0];
  #pragma unroll
  for (int c = 0; c < 8; ++c)
    x2v = fmaf(frelu(gat2[n*8+c] + bias2[c]), l2W[c], x2v);
  float hv = encp[n*64 + lane] + x1[n]*W1[9998*64 + lane]
           + x2v*W1[9999*64 + lane] + b1[lane];
  hb[wv][lane] = frelu(hv);
  __syncthreads();
  float t = 0.f;
  if (lane < 32) {
    float a2 = b2[lane];
    #pragma unroll
    for (int k = 0; k < 64; ++k) a2 = fmaf(hb[wv][k], W2[k*32 + lane], a2);
    t = frelu(a2) * W3[lane];
  }
  #pragma unroll
  for (int m = 1; m < 64; m <<= 1) t += __shfl_xor(t, m, 64);
  if (lane == 0) out[n] = t + b3[0];
}

// ---------------------------------------------------------------------------
extern "C" void kernel_launch(void* const* d_in, const int* in_sizes, int n_in,
                              void* d_out, int out_size, void* d_ws, size_t ws_size,
                              hipStream_t stream){
  (void)in_sizes; (void)n_in; (void)out_size; (void)ws_size;
  const float* x    = (const float*)d_in[0];
  const int*   ei   = (const int*)  d_in[1];
  const float* Wl1  = (const float*)d_in[2];
  const float* bl1  = (const float*)d_in[3];
  const float* Wr1  = (const float*)d_in[4];
  const float* br1  = (const float*)d_in[5];
  const float* att1 = (const float*)d_in[6];
  const float* bias1= (const float*)d_in[7];
  const float* l1W  = (const float*)d_in[8];
  const float* l1b  = (const float*)d_in[9];
  const float* Wl2  = (const float*)d_in[10];
  const float* bl2  = (const float*)d_in[11];
  const float* Wr2  = (const float*)d_in[12];
  const float* br2  = (const float*)d_in[13];
  const float* att2 = (const float*)d_in[14];
  const float* bias2= (const float*)d_in[15];
  const float* l2W  = (const float*)d_in[16];
  const float* l2b  = (const float*)d_in[17];
  const float* eW1  = (const float*)d_in[18];
  const float* eb1  = (const float*)d_in[19];
  const float* eW2  = (const float*)d_in[20];
  const float* eb2  = (const float*)d_in[21];
  const float* eW3  = (const float*)d_in[22];
  const float* eb3  = (const float*)d_in[23];

  float* ws = (float*)d_ws;
  size_t off = 0;
  auto alloc = [&](size_t nel){ float* pp = ws + off; off += (nel + 63) & ~size_t(63); return pp; };
  _Float16* Wimg = (_Float16*)alloc((size_t)160*CHWP/2);
  float* elog   = alloc((size_t)(NEDGE+NNODE)*2);
  // contiguous zero block [xl1 .. gat2] = ZN floats:
  float* xl1    = alloc(NNODE*8);
  float* xr1    = alloc(NNODE*8);
  float* encp   = alloc(NNODE*64);
  float* denom1 = alloc(NNODE*2);
  float* gat1   = alloc(NNODE*8);
  float* denom2 = alloc(NNODE*2);
  float* gat2   = alloc(NNODE*8);
  float* x1a    = alloc(NNODE);

  const int ET = NEDGE + NNODE;
  const int eb = (ET + 255)/256;

  prep_wt<<<(160*CHWP + 255)/256, 256, 0, stream>>>(Wl1, Wr1, eW1, Wimg, xl1);

  k1_fused<<<157*KSPLIT, 256, 0, stream>>>(x, Wimg, bl1, br1, xl1, xr1, encp);

  edgeA1<<<eb, 256, 0, stream>>>(ei, xl1, xr1, att1, elog, denom1);
  edgeB1<<<eb, 256, 0, stream>>>(ei, elog, denom1, xl1, gat1);
  node_x1<<<(NNODE+255)/256, 256, 0, stream>>>(gat1, bias1, l1W, l1b, x1a);

  edgeA2<<<eb, 256, 0, stream>>>(ei, x1a, Wl2, bl2, Wr2, br2, att2, elog, denom2);
  edgeB2<<<eb, 256, 0, stream>>>(ei, elog, denom2, x1a, Wl2, bl2, gat2);

  enc_finish<<<NNODE/4, 256, 0, stream>>>(encp, x1a, gat2, bias2, l2W, l2b,
                                          eW1, eb1, eW2, eb2, eW3, eb3,
                                          (float*)d_out);
}